// Round 5
// baseline (84.981 us; speedup 1.0000x reference)
//
#include <hip/hip_runtime.h>

// Spatial transformer (bilinear grid sample).
//   U: [B=8, C=64, H=256, W=256] f32, theta: [B=8, 2, N=65536] f32
//   out: [B=8, C=64, 256, 256] f32
// Pass 1: NCHW f32 -> NHWC bf16 transpose into d_ws (NT loads on U).
// Pass 2: bilinear gather from bf16 NHWC (L3-resident), 16B/lane corner
//         loads, coalesced NT NCHW store. 128 px per block.

#define B_  8
#define C_  64
#define H_  256
#define W_  256
#define N_  65536   // H*W = out_h*out_w
#define OW_ 256

typedef float          vfloat4  __attribute__((ext_vector_type(4)));
typedef unsigned short vushort8 __attribute__((ext_vector_type(8)));

static __device__ __forceinline__ unsigned short f2bf(float f) {
    unsigned int bits = __float_as_uint(f);
    bits += 0x7fffu + ((bits >> 16) & 1u);   // round-to-nearest-even
    return (unsigned short)(bits >> 16);
}
static __device__ __forceinline__ float bf2f(unsigned short u) {
    return __uint_as_float(((unsigned int)u) << 16);
}

// ---------- Pass 1: NCHW f32 -> NHWC bf16 (64 px x 64 ch tiles) ----------
__global__ __launch_bounds__(256) void transpose_to_bf16_nhwc(
    const float* __restrict__ U, unsigned short* __restrict__ V)
{
    __shared__ float tile[64][65];
    int blk = blockIdx.x;           // 0..8191
    int b   = blk >> 10;            // 1024 tiles per batch
    int p0  = (blk & 1023) << 6;    // starting pixel
    int t   = threadIdx.x;

    const float* Ub = U + (size_t)b * C_ * N_;
    int pq = t & 15;                // pixel quad
#pragma unroll
    for (int i = 0; i < 4; ++i) {
        int c = (t >> 4) + (i << 4);      // 0..63
        vfloat4 v = __builtin_nontemporal_load(
            reinterpret_cast<const vfloat4*>(Ub + (size_t)c * N_ + p0 + (pq << 2)));
        tile[c][(pq << 2) + 0] = v.x;
        tile[c][(pq << 2) + 1] = v.y;
        tile[c][(pq << 2) + 2] = v.z;
        tile[c][(pq << 2) + 3] = v.w;
    }
    __syncthreads();

    // Write: each lane packs 8 channels (16B bf16) of one pixel.
    unsigned short* Vb = V + (size_t)b * N_ * C_;
    int c8 = t & 7;                 // channel octet
#pragma unroll
    for (int i = 0; i < 2; ++i) {
        int p = (t >> 3) + (i << 5);      // 0..63
        uint4 pack;
        pack.x = (unsigned int)f2bf(tile[(c8 << 3) + 0][p]) |
                 ((unsigned int)f2bf(tile[(c8 << 3) + 1][p]) << 16);
        pack.y = (unsigned int)f2bf(tile[(c8 << 3) + 2][p]) |
                 ((unsigned int)f2bf(tile[(c8 << 3) + 3][p]) << 16);
        pack.z = (unsigned int)f2bf(tile[(c8 << 3) + 4][p]) |
                 ((unsigned int)f2bf(tile[(c8 << 3) + 5][p]) << 16);
        pack.w = (unsigned int)f2bf(tile[(c8 << 3) + 6][p]) |
                 ((unsigned int)f2bf(tile[(c8 << 3) + 7][p]) << 16);
        *reinterpret_cast<uint4*>(Vb + (size_t)(p0 + p) * C_ + (c8 << 3)) = pack;
    }
}

// ---------- Pass 2: bilinear gather (bf16 NHWC), store f32 NCHW ----------
// 128 output pixels per block; lane covers 8 channels (16B) per corner load.
__global__ __launch_bounds__(256) void st_gather_bf16(
    const unsigned short* __restrict__ V,
    const float* __restrict__ theta,
    float* __restrict__ out)
{
    __shared__ int   s_o00[128], s_o10[128], s_o01[128], s_o11[128];
    __shared__ float s_wa[128], s_wb[128], s_wc[128], s_wd[128];
    __shared__ float s_out[128][65];

    int blk = blockIdx.x;           // 0..4095
    int b   = blk >> 9;             // 512 blocks per batch
    int n0  = (blk & 511) << 7;     // 128 output pixels per block
    int t    = threadIdx.x;
    int lane = t & 63;
    int w    = t >> 6;

    // Phase A: threads 0..127 compute coords + weights.
    if (t < 128) {
        int n   = n0 + t;
        int col = n & (OW_ - 1);
        int row = n >> 8;
        const float step = 2.0f / 255.0f;
        float gx = -1.0f + (float)col * step;
        float gy = -1.0f + (float)row * step;
        const float* th = theta + (size_t)b * 2 * N_;
        float tx = __builtin_nontemporal_load(th + n);
        float ty = __builtin_nontemporal_load(th + N_ + n);
        float x = (tx + gx + 1.0f) * 127.5f;
        float y = (ty + gy + 1.0f) * 127.5f;
        float x0f = floorf(x), y0f = floorf(y);
        int x0 = min(max((int)x0f,     0), W_ - 2);
        int x1 = min(max((int)x0f + 1, 0), W_ - 1);
        int y0 = min(max((int)y0f,     0), H_ - 2);
        int y1 = min(max((int)y0f + 1, 0), H_ - 1);
        float x0w = (float)x0, x1w = (float)x1;
        float y0w = (float)y0, y1w = (float)y1;
        s_wa[t] = (x1w - x) * (y1w - y);
        s_wb[t] = (x1w - x) * (y - y0w);
        s_wc[t] = (x - x0w) * (y1w - y);
        s_wd[t] = (x - x0w) * (y - y0w);
        s_o00[t] = y0 * W_ + x0;
        s_o10[t] = y1 * W_ + x0;
        s_o01[t] = y0 * W_ + x1;
        s_o11[t] = y1 * W_ + x1;
    }
    __syncthreads();

    // Phase B: each wave handles 32 pixels, 8 at a time; 8 lanes per pixel.
    const unsigned short* Vb = V + (size_t)b * N_ * C_;
    int c8 = lane & 7;              // channel octet: 8 channels = 16B
    int c0 = c8 << 3;
#pragma unroll
    for (int i = 0; i < 4; ++i) {
        int p = (w << 5) + (i << 3) + (lane >> 3);
        float wa = s_wa[p], wb = s_wb[p], wc = s_wc[p], wd = s_wd[p];
        vushort8 A = *reinterpret_cast<const vushort8*>(Vb + ((size_t)s_o00[p] << 6) + c0);
        vushort8 Bv = *reinterpret_cast<const vushort8*>(Vb + ((size_t)s_o10[p] << 6) + c0);
        vushort8 Cc = *reinterpret_cast<const vushort8*>(Vb + ((size_t)s_o01[p] << 6) + c0);
        vushort8 D = *reinterpret_cast<const vushort8*>(Vb + ((size_t)s_o11[p] << 6) + c0);
#pragma unroll
        for (int k = 0; k < 8; ++k) {
            s_out[p][c0 + k] = wa * bf2f(A[k]) + wb * bf2f(Bv[k])
                             + wc * bf2f(Cc[k]) + wd * bf2f(D[k]);
        }
    }
    __syncthreads();

    // Phase C: coalesced NCHW store: lane writes float4 (4 consecutive px).
    float* ob = out + (size_t)b * C_ * N_ + n0;
    int p4 = t & 31;                // pixel quad index (32 quads = 128 px)
#pragma unroll
    for (int i = 0; i < 8; ++i) {
        int c = (t >> 5) + (i << 3);      // 0..63
        vfloat4 v;
        v.x = s_out[(p4 << 2) + 0][c];
        v.y = s_out[(p4 << 2) + 1][c];
        v.z = s_out[(p4 << 2) + 2][c];
        v.w = s_out[(p4 << 2) + 3][c];
        __builtin_nontemporal_store(v, reinterpret_cast<vfloat4*>(ob + (size_t)c * N_ + (p4 << 2)));
    }
}

// ---------- Fallback (direct NCHW gather) if workspace too small ----------
__global__ __launch_bounds__(256) void st_bilinear_direct(
    const float* __restrict__ U,
    const float* __restrict__ theta,
    float* __restrict__ out)
{
    int idx = blockIdx.x * blockDim.x + threadIdx.x;
    int b = idx >> 16;
    int n = idx & (N_ - 1);
    int col = n & (OW_ - 1);
    int row = n >> 8;
    const float step = 2.0f / 255.0f;
    float gx = -1.0f + (float)col * step;
    float gy = -1.0f + (float)row * step;
    const float* th = theta + (size_t)b * 2 * N_;
    float x = (th[n]      + gx + 1.0f) * 127.5f;
    float y = (th[N_ + n] + gy + 1.0f) * 127.5f;
    float x0f = floorf(x), y0f = floorf(y);
    int x0 = min(max((int)x0f,     0), W_ - 2);
    int x1 = min(max((int)x0f + 1, 0), W_ - 1);
    int y0 = min(max((int)y0f,     0), H_ - 2);
    int y1 = min(max((int)y0f + 1, 0), H_ - 1);
    float x0w = (float)x0, x1w = (float)x1;
    float y0w = (float)y0, y1w = (float)y1;
    float wa = (x1w - x) * (y1w - y);
    float wb = (x1w - x) * (y - y0w);
    float wc = (x - x0w) * (y1w - y);
    float wd = (x - x0w) * (y - y0w);
    const float* Ub = U + (size_t)b * C_ * N_;
    int o00 = y0 * W_ + x0, o10 = y1 * W_ + x0;
    int o01 = y0 * W_ + x1, o11 = y1 * W_ + x1;
    float* outp = out + (size_t)b * C_ * (size_t)N_ + n;
#pragma unroll 8
    for (int c = 0; c < C_; ++c) {
        const float* Uc = Ub + (size_t)c * N_;
        outp[(size_t)c * N_] = wa * Uc[o00] + wb * Uc[o10] + wc * Uc[o01] + wd * Uc[o11];
    }
}

extern "C" void kernel_launch(void* const* d_in, const int* in_sizes, int n_in,
                              void* d_out, int out_size, void* d_ws, size_t ws_size,
                              hipStream_t stream) {
    const float* U     = (const float*)d_in[0];
    const float* theta = (const float*)d_in[1];
    float* out = (float*)d_out;

    const size_t v_bytes = (size_t)B_ * N_ * C_ * sizeof(unsigned short);   // 64 MB
    if (ws_size >= v_bytes) {
        unsigned short* V = (unsigned short*)d_ws;
        transpose_to_bf16_nhwc<<<B_ * (N_ / 64), 256, 0, stream>>>(U, V);
        st_gather_bf16<<<B_ * (N_ / 128), 256, 0, stream>>>(V, theta, out);
    } else {
        int total = B_ * N_;
        st_bilinear_direct<<<(total + 255) / 256, 256, 0, stream>>>(U, theta, out);
    }
}

// Round 6
// 65.716 us; speedup vs baseline: 1.2932x; 1.2932x over previous
//
#include <hip/hip_runtime.h>

// Spatial transformer (bilinear grid sample).
//   U: [B=8, C=64, H=256, W=256] f32, theta: [B=8, 2, N=65536] f32
//   out: [B=8, C=64, 256, 256] f32
// Pass 1: NCHW f32 -> NHWC bf16 transpose into d_ws.
// Pass 2: bilinear gather from bf16 NHWC (L2/L3-resident), coalesced NCHW
//         NT store. Both kernels use identical XCD-chunked block swizzle so
//         each XCD owns one batch image's V (L2 locality for the 4x reuse).

#define B_  8
#define C_  64
#define H_  256
#define W_  256
#define N_  65536   // H*W = out_h*out_w
#define OW_ 256
#define NXCD 8

typedef float vfloat4 __attribute__((ext_vector_type(4)));

static __device__ __forceinline__ unsigned short f2bf(float f) {
    unsigned int bits = __float_as_uint(f);
    bits += 0x7fffu + ((bits >> 16) & 1u);   // round-to-nearest-even
    return (unsigned short)(bits >> 16);
}
static __device__ __forceinline__ float bf2f(unsigned short u) {
    return __uint_as_float(((unsigned int)u) << 16);
}

// XCD-chunked swizzle: hw-consecutive blocks round-robin across XCDs; remap
// so each XCD gets a contiguous chunk of logical blocks. nwg must be %8==0.
static __device__ __forceinline__ int xcd_swizzle(int bid, int nwg) {
    int cpx = nwg >> 3;                 // chunks per XCD
    return (bid & (NXCD - 1)) * cpx + (bid >> 3);
}

// ---------- Pass 1: NCHW f32 -> NHWC bf16 (64 px x 64 ch tiles) ----------
__global__ __launch_bounds__(256) void transpose_to_bf16_nhwc(
    const float* __restrict__ U, unsigned short* __restrict__ V)
{
    __shared__ float tile[64][65];
    int blk = xcd_swizzle(blockIdx.x, B_ * (N_ / 64));   // 0..8191
    int b   = blk >> 10;            // 1024 tiles per batch
    int p0  = (blk & 1023) << 6;    // starting pixel
    int t   = threadIdx.x;

    const float* Ub = U + (size_t)b * C_ * N_;
    // Read: float4 per lane. 16-lane groups read 256B contiguous per channel.
    int pq = t & 15;                // pixel quad
#pragma unroll
    for (int i = 0; i < 4; ++i) {
        int c = (t >> 4) + (i << 4);      // 0..63
        vfloat4 v = *reinterpret_cast<const vfloat4*>(Ub + (size_t)c * N_ + p0 + (pq << 2));
        tile[c][(pq << 2) + 0] = v.x;
        tile[c][(pq << 2) + 1] = v.y;
        tile[c][(pq << 2) + 2] = v.z;
        tile[c][(pq << 2) + 3] = v.w;
    }
    __syncthreads();

    // Write: each lane packs 8 channels (16B bf16) of one pixel.
    unsigned short* Vb = V + (size_t)b * N_ * C_;
    int c8 = t & 7;                 // channel octet
#pragma unroll
    for (int i = 0; i < 2; ++i) {
        int p = (t >> 3) + (i << 5);      // 0..63
        uint4 pack;
        pack.x = (unsigned int)f2bf(tile[(c8 << 3) + 0][p]) |
                 ((unsigned int)f2bf(tile[(c8 << 3) + 1][p]) << 16);
        pack.y = (unsigned int)f2bf(tile[(c8 << 3) + 2][p]) |
                 ((unsigned int)f2bf(tile[(c8 << 3) + 3][p]) << 16);
        pack.z = (unsigned int)f2bf(tile[(c8 << 3) + 4][p]) |
                 ((unsigned int)f2bf(tile[(c8 << 3) + 5][p]) << 16);
        pack.w = (unsigned int)f2bf(tile[(c8 << 3) + 6][p]) |
                 ((unsigned int)f2bf(tile[(c8 << 3) + 7][p]) << 16);
        *reinterpret_cast<uint4*>(Vb + (size_t)(p0 + p) * C_ + (c8 << 3)) = pack;
    }
}

// ---------- Pass 2: bilinear gather (bf16 NHWC), store f32 NCHW ----------
__global__ __launch_bounds__(256) void st_gather_bf16(
    const unsigned short* __restrict__ V,
    const float* __restrict__ theta,
    float* __restrict__ out)
{
    __shared__ int   s_o00[64], s_o10[64], s_o01[64], s_o11[64];
    __shared__ float s_wa[64], s_wb[64], s_wc[64], s_wd[64];
    __shared__ float s_out[64][65];

    int blk = xcd_swizzle(blockIdx.x, B_ * (N_ / 64));   // 0..8191
    int b   = blk >> 10;
    int n0  = (blk & 1023) << 6;    // 64 output pixels per block
    int t    = threadIdx.x;
    int lane = t & 63;
    int w    = t >> 6;

    if (t < 64) {
        int n   = n0 + t;
        int col = n & (OW_ - 1);
        int row = n >> 8;
        const float step = 2.0f / 255.0f;
        float gx = -1.0f + (float)col * step;
        float gy = -1.0f + (float)row * step;
        const float* th = theta + (size_t)b * 2 * N_;
        float x = (th[n]      + gx + 1.0f) * 127.5f;
        float y = (th[N_ + n] + gy + 1.0f) * 127.5f;
        float x0f = floorf(x), y0f = floorf(y);
        int x0 = min(max((int)x0f,     0), W_ - 2);
        int x1 = min(max((int)x0f + 1, 0), W_ - 1);
        int y0 = min(max((int)y0f,     0), H_ - 2);
        int y1 = min(max((int)y0f + 1, 0), H_ - 1);
        float x0w = (float)x0, x1w = (float)x1;
        float y0w = (float)y0, y1w = (float)y1;
        s_wa[t] = (x1w - x) * (y1w - y);
        s_wb[t] = (x1w - x) * (y - y0w);
        s_wc[t] = (x - x0w) * (y1w - y);
        s_wd[t] = (x - x0w) * (y - y0w);
        s_o00[t] = y0 * W_ + x0;
        s_o10[t] = y1 * W_ + x0;
        s_o01[t] = y0 * W_ + x1;
        s_o11[t] = y1 * W_ + x1;
    }
    __syncthreads();

    // Each wave handles 16 pixels, 4 at a time; lane covers 4 channels (8B).
    const unsigned short* Vb = V + (size_t)b * N_ * C_;
    int cq = lane & 15;             // channel quad
#pragma unroll
    for (int i = 0; i < 4; ++i) {
        int p = (w << 4) + (i << 2) + (lane >> 4);
        float wa = s_wa[p], wb = s_wb[p], wc = s_wc[p], wd = s_wd[p];
        ushort4 A  = *reinterpret_cast<const ushort4*>(Vb + ((size_t)s_o00[p] << 6) + (cq << 2));
        ushort4 Bv = *reinterpret_cast<const ushort4*>(Vb + ((size_t)s_o10[p] << 6) + (cq << 2));
        ushort4 Cc = *reinterpret_cast<const ushort4*>(Vb + ((size_t)s_o01[p] << 6) + (cq << 2));
        ushort4 D  = *reinterpret_cast<const ushort4*>(Vb + ((size_t)s_o11[p] << 6) + (cq << 2));
        s_out[p][(cq << 2) + 0] = wa * bf2f(A.x) + wb * bf2f(Bv.x) + wc * bf2f(Cc.x) + wd * bf2f(D.x);
        s_out[p][(cq << 2) + 1] = wa * bf2f(A.y) + wb * bf2f(Bv.y) + wc * bf2f(Cc.y) + wd * bf2f(D.y);
        s_out[p][(cq << 2) + 2] = wa * bf2f(A.z) + wb * bf2f(Bv.z) + wc * bf2f(Cc.z) + wd * bf2f(D.z);
        s_out[p][(cq << 2) + 3] = wa * bf2f(A.w) + wb * bf2f(Bv.w) + wc * bf2f(Cc.w) + wd * bf2f(D.w);
    }
    __syncthreads();

    // Coalesced NCHW store: lane writes float4 (4 consecutive pixels, 1 channel).
    float* ob = out + (size_t)b * C_ * N_ + n0;
    int p4 = t & 15;
#pragma unroll
    for (int i = 0; i < 4; ++i) {
        int c = (t >> 4) + (i << 4);      // 0..63
        vfloat4 v;
        v.x = s_out[(p4 << 2) + 0][c];
        v.y = s_out[(p4 << 2) + 1][c];
        v.z = s_out[(p4 << 2) + 2][c];
        v.w = s_out[(p4 << 2) + 3][c];
        __builtin_nontemporal_store(v, reinterpret_cast<vfloat4*>(ob + (size_t)c * N_ + (p4 << 2)));
    }
}

// ---------- Fallback (direct NCHW gather) if workspace too small ----------
__global__ __launch_bounds__(256) void st_bilinear_direct(
    const float* __restrict__ U,
    const float* __restrict__ theta,
    float* __restrict__ out)
{
    int idx = blockIdx.x * blockDim.x + threadIdx.x;
    int b = idx >> 16;
    int n = idx & (N_ - 1);
    int col = n & (OW_ - 1);
    int row = n >> 8;
    const float step = 2.0f / 255.0f;
    float gx = -1.0f + (float)col * step;
    float gy = -1.0f + (float)row * step;
    const float* th = theta + (size_t)b * 2 * N_;
    float x = (th[n]      + gx + 1.0f) * 127.5f;
    float y = (th[N_ + n] + gy + 1.0f) * 127.5f;
    float x0f = floorf(x), y0f = floorf(y);
    int x0 = min(max((int)x0f,     0), W_ - 2);
    int x1 = min(max((int)x0f + 1, 0), W_ - 1);
    int y0 = min(max((int)y0f,     0), H_ - 2);
    int y1 = min(max((int)y0f + 1, 0), H_ - 1);
    float x0w = (float)x0, x1w = (float)x1;
    float y0w = (float)y0, y1w = (float)y1;
    float wa = (x1w - x) * (y1w - y);
    float wb = (x1w - x) * (y - y0w);
    float wc = (x - x0w) * (y1w - y);
    float wd = (x - x0w) * (y - y0w);
    const float* Ub = U + (size_t)b * C_ * N_;
    int o00 = y0 * W_ + x0, o10 = y1 * W_ + x0;
    int o01 = y0 * W_ + x1, o11 = y1 * W_ + x1;
    float* outp = out + (size_t)b * C_ * (size_t)N_ + n;
#pragma unroll 8
    for (int c = 0; c < C_; ++c) {
        const float* Uc = Ub + (size_t)c * N_;
        outp[(size_t)c * N_] = wa * Uc[o00] + wb * Uc[o10] + wc * Uc[o01] + wd * Uc[o11];
    }
}

extern "C" void kernel_launch(void* const* d_in, const int* in_sizes, int n_in,
                              void* d_out, int out_size, void* d_ws, size_t ws_size,
                              hipStream_t stream) {
    const float* U     = (const float*)d_in[0];
    const float* theta = (const float*)d_in[1];
    float* out = (float*)d_out;

    const size_t v_bytes = (size_t)B_ * N_ * C_ * sizeof(unsigned short);   // 64 MB
    if (ws_size >= v_bytes) {
        unsigned short* V = (unsigned short*)d_ws;
        int blocks = B_ * (N_ / 64);   // 8192, %8 == 0
        transpose_to_bf16_nhwc<<<blocks, 256, 0, stream>>>(U, V);
        st_gather_bf16<<<blocks, 256, 0, stream>>>(V, theta, out);
    } else {
        int total = B_ * N_;
        st_bilinear_direct<<<(total + 255) / 256, 256, 0, stream>>>(U, theta, out);
    }
}